// Round 11
// baseline (347.696 us; speedup 1.0000x reference)
//
#include <hip/hip_runtime.h>
#include <math.h>

namespace {

constexpr int N   = 20000;
constexpr int E   = 250000;
constexpr int B   = 8;
constexpr int D   = 32;
constexpr int R2  = 100;
constexpr int L   = 6;
constexpr int NEG = 32;
constexpr float EPSF = 1e-6f;

constexpr int BD = B * D;        // 256
constexpr int NPB = 8;           // nodes per stats-group (panel granularity)
constexpr int WSZ  = 26624;      // per-layer split-weight block (shorts)
constexpr int NSCB = (N + 255) / 256;   // scan blocks = 79
constexpr int NBLK = N / NPB;           // 2500 node-groups
constexpr int SBLK = 64 * 128;          // stats panel shorts per group
constexpr int GPB  = 5;                 // groups per k_gemm block
constexpr int GBLK = NBLK / GPB;        // 500 k_gemm blocks
constexpr int RELSZ = L * B * R2 * D;   // 153600

typedef __attribute__((ext_vector_type(8))) short bf16x8;
typedef __attribute__((ext_vector_type(4))) float f32x4;
typedef _Float16 half4_t __attribute__((ext_vector_type(4)));
typedef _Float16 half8_t __attribute__((ext_vector_type(8)));
typedef float float4_t __attribute__((ext_vector_type(4)));

__device__ inline unsigned short f2bf(float x) {          // RNE f32->bf16
  unsigned int u = __float_as_uint(x);
  unsigned int r = u + 0x7FFF + ((u >> 16) & 1);
  return (unsigned short)(r >> 16);
}
__device__ inline float bf2f(unsigned short h) {
  return __uint_as_float(((unsigned int)h) << 16);
}
__device__ inline void split2(float v, unsigned short& hi, unsigned short& lo) {
  hi = f2bf(v);
  lo = f2bf(v - bf2f(hi));
}

// ---------------- init ----------------
__global__ void k_init(unsigned int* x0i, int* cnt, float* meanacc) {
  int i = blockIdx.x * blockDim.x + threadIdx.x;
  int stride = gridDim.x * blockDim.x;
  for (int t = i; t < N * BD / 2; t += stride) x0i[t] = 0u;  // fp16 x0 = 0
  for (int t = i; t < N; t += stride) cnt[t] = 0;
  if (i == 0) meanacc[0] = 0.f;
}

// edge-dst histogram; LAST block instead does query gather + boundary scatter
__global__ void k_countq(const int* __restrict__ edge_dst, int* cnt,
                         const int* __restrict__ r_index, const int* __restrict__ h_index,
                         const float* __restrict__ query_emb, float* query, _Float16* x0) {
  if (blockIdx.x == gridDim.x - 1) {
    int tid = threadIdx.x;          // 256
    int b = tid >> 5, d = tid & 31;
    float q = query_emb[r_index[b] * D + d];
    query[tid] = q;
    x0[h_index[b] * BD + tid] = (_Float16)q;   // x0 zeroed by k_init
    return;
  }
  int e = blockIdx.x * blockDim.x + threadIdx.x;
  if (e < E) atomicAdd(&cnt[edge_dst[e]], 1);
}

// scan A: per-block local scan + block sums; also fill[i]=0 and log-sum
__global__ void k_scanA(const int* __restrict__ cnt, int* row_start, int* bsum,
                        int* fill, float* meanacc) {
  __shared__ int wsum[4];
  __shared__ float fsum[4];
  int tid = threadIdx.x;            // 256
  int lane = tid & 63, wv = tid >> 6;
  int i = blockIdx.x * 256 + tid;
  int v = (i < N) ? cnt[i] : 0;
  int x = v;
  for (int o = 1; o < 64; o <<= 1) {
    int y = __shfl_up(x, o, 64);
    if (lane >= o) x += y;
  }
  if (lane == 63) wsum[wv] = x;
  __syncthreads();
  int add = 0;
  for (int w = 0; w < wv; ++w) add += wsum[w];
  if (i < N) {
    row_start[i] = x - v + add;     // block-local exclusive
    fill[i] = 0;
  }
  if (tid == 255) bsum[blockIdx.x] = add + x; // block total
  // fused log-degree sum
  float lv = (i < N) ? logf((float)(v + 1)) : 0.f;
  for (int o = 32; o > 0; o >>= 1) lv += __shfl_down(lv, o, 64);
  if (lane == 0) fsum[wv] = lv;
  __syncthreads();
  if (tid == 0) atomicAdd(meanacc, fsum[0] + fsum[1] + fsum[2] + fsum[3]);
}

// B) scan the block sums (1 wave handles up to 128 blocks)
__global__ void k_scanB(const int* __restrict__ bsum, int* boff, int* row_start) {
  int lane = threadIdx.x;           // 64
  int a0 = (lane < NSCB) ? bsum[lane] : 0;
  int a1 = (64 + lane < NSCB) ? bsum[64 + lane] : 0;
  int x = a0;
  for (int o = 1; o < 64; o <<= 1) {
    int y = __shfl_up(x, o, 64);
    if (lane >= o) x += y;
  }
  int tot0 = __shfl(x, 63, 64);
  int x1 = a1;
  for (int o = 1; o < 64; o <<= 1) {
    int y = __shfl_up(x1, o, 64);
    if (lane >= o) x1 += y;
  }
  if (lane < NSCB) boff[lane] = x - a0;
  if (64 + lane < NSCB) boff[64 + lane] = tot0 + x1 - a1;
  if (lane == 63) row_start[N] = tot0 + __shfl(x1, 63, 64);   // == E
}

// C) add block offsets
__global__ void k_scanC(int* row_start, const int* __restrict__ boff) {
  int i = blockIdx.x * 256 + threadIdx.x;
  if (i < N) row_start[i] += boff[blockIdx.x];
}

// scatter edges into CSR slots; pack src | (type<<16)
__global__ void k_scatter(const int* __restrict__ edge_src, const int* __restrict__ edge_dst,
                          const int* __restrict__ edge_type, const int* __restrict__ row_start,
                          int* fill, int* packed) {
  int e = blockIdx.x * blockDim.x + threadIdx.x;
  if (e < E) {
    int dn = edge_dst[e];
    int pos = atomicAdd(&fill[dn], 1);
    packed[row_start[dn] + pos] = edge_src[e] | (edge_type[e] << 16);
  }
}

__global__ void k_scales(const int* __restrict__ cnt, const float* __restrict__ meanacc,
                         float* scales) {
  int i = blockIdx.x * blockDim.x + threadIdx.x;
  if (i < N) {
    float m = meanacc[0] / (float)N;
    float s = logf((float)(cnt[i] + 1)) / m;
    scales[i * 3 + 0] = 1.f;
    scales[i * 3 + 1] = s;
    scales[i * 3 + 2] = 1.f / fmaxf(s, 0.01f);
  }
}

// fused prep: rel (fp16) + split weights (bf16 hi/lo)
__global__ void k_prep(const float* __restrict__ query, const float* __restrict__ Wr,
                       const float* __restrict__ br, _Float16* rel,
                       const float* __restrict__ Wl, short* WT) {
  int o = blockIdx.x * blockDim.x + threadIdx.x;
  if (o < RELSZ) {
    int d = o & 31;
    int r = (o >> 5) % R2;
    int b = (o / (R2 * D)) % B;
    int l = o / (B * R2 * D);
    int rd = r * D + d;
    const float4* wrow = (const float4*)(Wr + ((size_t)l * R2 * D + rd) * D);
    const float* q = query + b * D;
    float acc = br[l * R2 * D + rd];
#pragma unroll
    for (int k = 0; k < 8; ++k) {
      float4 w4 = wrow[k];
      acc = fmaf(q[4 * k + 0], w4.x, acc);
      acc = fmaf(q[4 * k + 1], w4.y, acc);
      acc = fmaf(q[4 * k + 2], w4.z, acc);
      acc = fmaf(q[4 * k + 3], w4.w, acc);
    }
    rel[o] = (_Float16)acc;
    return;
  }
  int t0 = o - RELSZ;
  if (t0 >= L * 13312) return;
  int l = t0 / 13312, t = t0 % 13312;
  int j = t / 416, k = t % 416;
  float v = Wl[(size_t)l * 13312 + j * 416 + k];
  unsigned short hi, lo;
  split2(v, hi, lo);
  short* wt = WT + (size_t)l * WSZ;
  if (k < 32) {
    int dx = j * 32 + k;
    wt[dx] = (short)hi;
    wt[1024 + dx] = (short)lo;
  } else {
    int u = k - 32;
    int f = u / 3, s = u % 3;
    int df = (s * 32 + j) * 128 + f;
    wt[2048 + df] = (short)hi;
    wt[14336 + df] = (short)lo;
  }
}

// ---- aggregation kernel: 128 threads = 2 waves = 2 nodes per block ----
// (unchanged from R10: small blocks minimize max-of-degree retirement penalty)
__global__ __launch_bounds__(128) void k_agg(
    const _Float16* __restrict__ xin, const _Float16* __restrict__ rel_l,
    short* __restrict__ stath,
    const int* __restrict__ row_start, const int* __restrict__ packed,
    const int* __restrict__ h_index, const float* __restrict__ query) {
  int tid = threadIdx.x;
  int lane = tid & 63;
  int wv = __builtin_amdgcn_readfirstlane(tid >> 6);   // 0..1
  int node = blockIdx.x * 2 + wv;

  int ch4 = 4 * lane;
  int b = lane >> 3;
  int d0 = ch4 & 31;
  int hb = h_index[b];
  const _Float16* relb4 = rel_l + b * (R2 * D) + d0;
  const _Float16* xch = xin + ch4;
  int rs = row_start[node];
  int cntE = row_start[node + 1] - rs;

  float4_t s1 = {0.f, 0.f, 0.f, 0.f}, s2 = {0.f, 0.f, 0.f, 0.f};
  half4_t mxh = {(_Float16)-INFINITY, (_Float16)-INFINITY, (_Float16)-INFINITY, (_Float16)-INFINITY};
  half4_t mnh = {(_Float16)INFINITY, (_Float16)INFINITY, (_Float16)INFINITY, (_Float16)INFINITY};
  float4_t mx2 = {-INFINITY, -INFINITY, -INFINITY, -INFINITY};
  float4_t mn2 = {INFINITY, INFINITY, INFINITY, INFINITY};

  // -------- main loop: full batches, no predication --------
  int nfull = cntE >> 3;
  for (int t = 0; t < nfull; ++t) {
    int j0 = t * 8;
    int pk[8];
#pragma unroll
    for (int u = 0; u < 8; ++u) pk[u] = packed[rs + j0 + u];   // uniform -> s_load
    half4_t xv[8], rv[8];
#pragma unroll
    for (int u = 0; u < 8; ++u) xv[u] = *(const half4_t*)&xch[(pk[u] & 0xFFFF) * BD];
#pragma unroll
    for (int u = 0; u < 8; ++u) rv[u] = *(const half4_t*)&relb4[(pk[u] >> 16) * D];
#pragma unroll
    for (int u = 0; u < 8; ++u) {
      half4_t m = xv[u] * rv[u];                      // v_pk_mul_f16 x2
      mxh = __builtin_elementwise_max(mxh, m);        // v_pk_max_f16 x2
      mnh = __builtin_elementwise_min(mnh, m);        // v_pk_min_f16 x2
      float4_t mf = __builtin_convertvector(m, float4_t);
#pragma unroll
      for (int c = 0; c < 4; ++c) {
        s1[c] += mf[c];
        s2[c] = fmaf(mf[c], mf[c], s2[c]);
      }
    }
  }
  // -------- tail: one predicated clamped batch (f32 path) --------
  int rem = cntE & 7;
  if (rem) {
    int j0 = nfull * 8;
    int last = cntE - 1;
    int pk[8];
#pragma unroll
    for (int u = 0; u < 8; ++u) {
      int jj = j0 + u;
      pk[u] = packed[rs + (jj < cntE ? jj : last)];
    }
    half4_t xv[8], rv[8];
#pragma unroll
    for (int u = 0; u < 8; ++u) xv[u] = *(const half4_t*)&xch[(pk[u] & 0xFFFF) * BD];
#pragma unroll
    for (int u = 0; u < 8; ++u) rv[u] = *(const half4_t*)&relb4[(pk[u] >> 16) * D];
#pragma unroll
    for (int u = 0; u < 8; ++u) {
      bool ok = (j0 + u) < cntE;
      float4_t xf = __builtin_convertvector(xv[u], float4_t);
      float4_t rf = __builtin_convertvector(rv[u], float4_t);
#pragma unroll
      for (int c = 0; c < 4; ++c) {
        float m = xf[c] * rf[c];
        float mm = ok ? m : 0.f;
        s1[c] += mm;
        s2[c] = fmaf(mm, mm, s2[c]);
        mx2[c] = fmaxf(mx2[c], ok ? m : -INFINITY);
        mn2[c] = fminf(mn2[c], ok ? m : INFINITY);
      }
    }
  }
  // -------- boundary self-message + finalize --------
  float4_t mxF, mnF;
#pragma unroll
  for (int c = 0; c < 4; ++c) {
    mxF[c] = fmaxf((float)mxh[c], mx2[c]);
    mnF[c] = fminf((float)mnh[c], mn2[c]);
  }
  {
    const float* q4 = &query[ch4];
    bool isb = (hb == node);
#pragma unroll
    for (int c = 0; c < 4; ++c) {
      float m = isb ? q4[c] : 0.f;
      s1[c] += m;
      s2[c] = fmaf(m, m, s2[c]);
      mxF[c] = fmaxf(mxF[c], m);
      mnF[c] = fminf(mnF[c], m);
    }
  }
  float invdeg = 1.f / (float)(cntE + 1);

  unsigned int hw[8];
#pragma unroll
  for (int c = 0; c < 4; ++c) {
    float mean = s1[c] * invdeg, sq = s2[c] * invdeg;
    float sd = sqrtf(fmaxf(sq - mean * mean, EPSF));
    unsigned short h0 = f2bf(mean), h1 = f2bf(mxF[c]);
    unsigned short h2 = f2bf(mnF[c]), h3 = f2bf(sd);
    hw[2 * c]     = (unsigned)h0 | ((unsigned)h1 << 16);
    hw[2 * c + 1] = (unsigned)h2 | ((unsigned)h3 << 16);
  }
  int grp = node >> 3;
  int r = (node & 7) * 8 + b;               // panel row (node_local*8 + b)
  short* dh = stath + (size_t)grp * SBLK + r * 128 + 4 * d0;
  *(uint4*)dh = make_uint4(hw[0], hw[1], hw[2], hw[3]);
  *(uint4*)(dh + 8) = make_uint4(hw[4], hw[5], hw[6], hw[7]);
}

// ---- GEMM kernel: B register-resident (feat weights single bf16),
// GPB=5 groups per block (500 blocks), A double-buffer prefetch.
// x-part stays exact (fp16 A hi/lo x weight hi/lo). VGPR target <=128
// -> 4 waves/SIMD via __launch_bounds__(512, 4).
struct AFrag {
  bf16x8 AH[4];
  half8_t xv;
};

__global__ __launch_bounds__(512, 4) void k_gemm(
    const _Float16* __restrict__ xin, _Float16* __restrict__ xout,
    const short* __restrict__ stath,
    const short* __restrict__ WT_l, const float* __restrict__ bl_l,
    const float* __restrict__ scales) {
  int tid = threadIdx.x;
  int lane = tid & 63;
  int wv = __builtin_amdgcn_readfirstlane(tid >> 6);   // 0..7
  int mt = wv >> 1, nt = wv & 1;
  int li = lane & 15, kg = lane >> 4;
  int rowA = mt * 16 + li;
  int jc = nt * 16 + li;

  const short* wxh = WT_l;
  const short* wxl = WT_l + 1024;
  const short* wfh = WT_l + 2048;

  // B fragments: loaded ONCE (x hi/lo + feat hi only = 14 frags = 56 VGPR)
  bf16x8 BXH = *(const bf16x8*)&wxh[jc * 32 + kg * 8];
  bf16x8 BXL = *(const bf16x8*)&wxl[jc * 32 + kg * 8];
  bf16x8 BH[4][3];
#pragma unroll
  for (int step = 0; step < 4; ++step)
#pragma unroll
    for (int s = 0; s < 3; ++s)
      BH[step][s] = *(const bf16x8*)&wfh[s * 4096 + jc * 128 + step * 32 + kg * 8];

  int grp0 = blockIdx.x * GPB;

  auto loadA = [&](int g) {
    AFrag a;
    int grp = grp0 + g;
    const short* sh = stath + (size_t)grp * SBLK + rowA * 128 + kg * 8;
#pragma unroll
    for (int step = 0; step < 4; ++step) a.AH[step] = *(const bf16x8*)&sh[step * 32];
    a.xv = *(const half8_t*)&xin[(grp * NPB) * 256 + rowA * 32 + kg * 8];
    return a;
  };

  AFrag cur = loadA(0);
#pragma unroll
  for (int g = 0; g < GPB; ++g) {
    AFrag nxt;
    if (g + 1 < GPB) nxt = loadA(g + 1);   // issue next-group loads early

    int node0 = (grp0 + g) * NPB;
    bf16x8 axh, axl;
#pragma unroll
    for (int i = 0; i < 8; ++i) {
      unsigned short h, lo;
      split2((float)cur.xv[i], h, lo);     // fp16 -> bf16 hi/lo exact
      axh[i] = (short)h;
      axl[i] = (short)lo;
    }

    f32x4 acc0 = {0.f, 0.f, 0.f, 0.f};
    f32x4 acc1 = {0.f, 0.f, 0.f, 0.f};
    f32x4 acc2 = {0.f, 0.f, 0.f, 0.f};

    acc0 = __builtin_amdgcn_mfma_f32_16x16x32_bf16(axl, BXH, acc0, 0, 0, 0);
    acc0 = __builtin_amdgcn_mfma_f32_16x16x32_bf16(axh, BXL, acc0, 0, 0, 0);
    acc0 = __builtin_amdgcn_mfma_f32_16x16x32_bf16(axh, BXH, acc0, 0, 0, 0);
#pragma unroll
    for (int step = 0; step < 4; ++step) {
      acc0 = __builtin_amdgcn_mfma_f32_16x16x32_bf16(cur.AH[step], BH[step][0], acc0, 0, 0, 0);
      acc1 = __builtin_amdgcn_mfma_f32_16x16x32_bf16(cur.AH[step], BH[step][1], acc1, 0, 0, 0);
      acc2 = __builtin_amdgcn_mfma_f32_16x16x32_bf16(cur.AH[step], BH[step][2], acc2, 0, 0, 0);
    }

    // epilogue: scales per row, bias, relu, fp16 store
    // C/D layout: col = lane&15, row = (lane>>4)*4 + reg
    int rbase = mt * 16 + kg * 4;
    int node = node0 + (rbase >> 3);
    float sc1 = scales[node * 3 + 1];
    float sc2 = scales[node * 3 + 2];
    float bias = bl_l[jc & 31];
#pragma unroll
    for (int reg = 0; reg < 4; ++reg) {
      float v = acc0[reg] + sc1 * acc1[reg] + sc2 * acc2[reg] + bias;
      xout[node0 * 256 + (rbase + reg) * 32 + jc] = (_Float16)fmaxf(v, 0.f);
    }
    cur = nxt;
  }
}

// -------------- scoring head: one block per (b, neg) --------------
__global__ void k_score(const _Float16* __restrict__ xL, const float* __restrict__ query,
                        const int* __restrict__ t_index, const float* __restrict__ W1,
                        const float* __restrict__ b1, const float* __restrict__ W2,
                        const float* __restrict__ b2, float* outp) {
  int bn = blockIdx.x;             // b*NEG + neg
  int b = bn >> 5;
  int j = threadIdx.x;             // 64
  __shared__ float f[64];
  int t = t_index[bn];
  f[j] = (j < 32) ? (float)xL[t * BD + b * D + j] : query[b * D + (j - 32)];
  __syncthreads();
  const float* w1r = W1 + j * 64;
  float h = b1[j];
#pragma unroll
  for (int k = 0; k < 64; ++k) h = fmaf(f[k], w1r[k], h);
  h = fmaxf(h, 0.f);
  float p = h * W2[j];
#pragma unroll
  for (int o = 32; o > 0; o >>= 1) p += __shfl_down(p, o, 64);
  if (j == 0) outp[bn] = p + b2[0];
}

} // namespace

extern "C" void kernel_launch(void* const* d_in, const int* in_sizes, int n_in,
                              void* d_out, int out_size, void* d_ws, size_t ws_size,
                              hipStream_t stream) {
  const int* edge_src   = (const int*)d_in[0];
  const int* edge_dst   = (const int*)d_in[1];
  const int* edge_type  = (const int*)d_in[2];
  const int* h_index    = (const int*)d_in[3];
  const int* t_index    = (const int*)d_in[4];
  const int* r_index    = (const int*)d_in[5];
  const float* query_emb= (const float*)d_in[6];
  const float* Wr       = (const float*)d_in[7];
  const float* br       = (const float*)d_in[8];
  const float* Wl       = (const float*)d_in[9];
  const float* bl       = (const float*)d_in[10];
  const float* W1       = (const float*)d_in[11];
  const float* b1       = (const float*)d_in[12];
  const float* W2       = (const float*)d_in[13];
  const float* b2       = (const float*)d_in[14];
  float* outp = (float*)d_out;
  (void)in_sizes; (void)n_in; (void)out_size; (void)ws_size;

  char* w = (char*)d_ws;
  auto alloc = [&](size_t bytes) {
    char* p = w;
    w += (bytes + 511) & ~(size_t)511;
    return p;
  };
  _Float16* x0   = (_Float16*)alloc(sizeof(_Float16) * N * BD);
  _Float16* x1   = (_Float16*)alloc(sizeof(_Float16) * N * BD);
  short* stath   = (short*)alloc(sizeof(short) * (size_t)NBLK * SBLK);
  _Float16* rel  = (_Float16*)alloc(sizeof(_Float16) * RELSZ);
  short* WT      = (short*)alloc(sizeof(short) * L * WSZ);
  float* query   = (float*)alloc(sizeof(float) * BD);
  float* scales  = (float*)alloc(sizeof(float) * N * 3);
  float* meanacc = (float*)alloc(sizeof(float) * 16);
  int* row_start = (int*)alloc(sizeof(int) * (N + 1));
  int* cnt       = (int*)alloc(sizeof(int) * N);
  int* fill      = (int*)alloc(sizeof(int) * N);
  int* packed    = (int*)alloc(sizeof(int) * E);
  int* bsum      = (int*)alloc(sizeof(int) * 128);
  int* boff      = (int*)alloc(sizeof(int) * 128);

  k_init<<<2048, 256, 0, stream>>>((unsigned int*)x0, cnt, meanacc);
  k_countq<<<(E + 255) / 256 + 1, 256, 0, stream>>>(edge_dst, cnt, r_index, h_index,
                                                    query_emb, query, x0);
  k_scanA<<<NSCB, 256, 0, stream>>>(cnt, row_start, bsum, fill, meanacc);
  k_scanB<<<1, 64, 0, stream>>>(bsum, boff, row_start);
  k_scanC<<<NSCB, 256, 0, stream>>>(row_start, boff);
  k_scatter<<<(E + 255) / 256, 256, 0, stream>>>(edge_src, edge_dst, edge_type,
                                                 row_start, fill, packed);
  k_scales<<<(N + 255) / 256, 256, 0, stream>>>(cnt, meanacc, scales);
  k_prep<<<(RELSZ + L * 13312 + 255) / 256, 256, 0, stream>>>(query, Wr, br, rel, Wl, WT);

  const _Float16* xin = x0;
  _Float16* xout = x1;
  for (int l = 0; l < L; ++l) {
    k_agg<<<N / 2, 128, 0, stream>>>(xin, rel + (size_t)l * B * R2 * D,
                                     stath, row_start, packed, h_index, query);
    k_gemm<<<GBLK, 512, 0, stream>>>(xin, xout, stath,
                                     WT + (size_t)l * WSZ, bl + l * D, scales);
    const _Float16* t = xout;
    xout = (_Float16*)xin;
    xin = t;
  }
  // L is even -> final activations are back in x0 (== xin after last swap)
  k_score<<<B * NEG, 64, 0, stream>>>(xin, query, t_index, W1, b1, W2, b2, outp);
}

// Round 12
// 318.846 us; speedup vs baseline: 1.0905x; 1.0905x over previous
//
#include <hip/hip_runtime.h>
#include <math.h>

namespace {

constexpr int N   = 20000;
constexpr int E   = 250000;
constexpr int B   = 8;
constexpr int D   = 32;
constexpr int R2  = 100;
constexpr int L   = 6;
constexpr int NEG = 32;
constexpr float EPSF = 1e-6f;

constexpr int BD = B * D;        // 256
constexpr int NPB = 8;           // nodes per stats-group (panel granularity)
constexpr int WSZ  = 26624;      // per-layer split-weight block (shorts)
constexpr int NSCB = (N + 255) / 256;   // scan blocks = 79
constexpr int NBLK = N / NPB;           // 2500 node-groups
constexpr int SBLK = 64 * 128;          // stats panel shorts per group
constexpr int GPB  = 10;                // groups per k_gemm block
constexpr int GBLK = NBLK / GPB;        // 250 k_gemm blocks
constexpr int RELSZ = L * B * R2 * D;   // 153600

typedef __attribute__((ext_vector_type(8))) short bf16x8;
typedef __attribute__((ext_vector_type(4))) float f32x4;
typedef _Float16 half4_t __attribute__((ext_vector_type(4)));
typedef _Float16 half8_t __attribute__((ext_vector_type(8)));
typedef float float4_t __attribute__((ext_vector_type(4)));

__device__ inline unsigned short f2bf(float x) {          // RNE f32->bf16
  unsigned int u = __float_as_uint(x);
  unsigned int r = u + 0x7FFF + ((u >> 16) & 1);
  return (unsigned short)(r >> 16);
}
__device__ inline float bf2f(unsigned short h) {
  return __uint_as_float(((unsigned int)h) << 16);
}
__device__ inline void split2(float v, unsigned short& hi, unsigned short& lo) {
  hi = f2bf(v);
  lo = f2bf(v - bf2f(hi));
}

// ---------------- init ----------------
__global__ void k_init(unsigned int* x0i, int* cnt, float* meanacc) {
  int i = blockIdx.x * blockDim.x + threadIdx.x;
  int stride = gridDim.x * blockDim.x;
  for (int t = i; t < N * BD / 2; t += stride) x0i[t] = 0u;  // fp16 x0 = 0
  for (int t = i; t < N; t += stride) cnt[t] = 0;
  if (i == 0) meanacc[0] = 0.f;
}

// edge-dst histogram; LAST block instead does query gather + boundary scatter
__global__ void k_countq(const int* __restrict__ edge_dst, int* cnt,
                         const int* __restrict__ r_index, const int* __restrict__ h_index,
                         const float* __restrict__ query_emb, float* query, _Float16* x0) {
  if (blockIdx.x == gridDim.x - 1) {
    int tid = threadIdx.x;          // 256
    int b = tid >> 5, d = tid & 31;
    float q = query_emb[r_index[b] * D + d];
    query[tid] = q;
    x0[h_index[b] * BD + tid] = (_Float16)q;   // x0 zeroed by k_init
    return;
  }
  int e = blockIdx.x * blockDim.x + threadIdx.x;
  if (e < E) atomicAdd(&cnt[edge_dst[e]], 1);
}

// scan A: per-block local scan + block sums; also fill[i]=0 and log-sum
__global__ void k_scanA(const int* __restrict__ cnt, int* row_start, int* bsum,
                        int* fill, float* meanacc) {
  __shared__ int wsum[4];
  __shared__ float fsum[4];
  int tid = threadIdx.x;            // 256
  int lane = tid & 63, wv = tid >> 6;
  int i = blockIdx.x * 256 + tid;
  int v = (i < N) ? cnt[i] : 0;
  int x = v;
  for (int o = 1; o < 64; o <<= 1) {
    int y = __shfl_up(x, o, 64);
    if (lane >= o) x += y;
  }
  if (lane == 63) wsum[wv] = x;
  __syncthreads();
  int add = 0;
  for (int w = 0; w < wv; ++w) add += wsum[w];
  if (i < N) {
    row_start[i] = x - v + add;     // block-local exclusive
    fill[i] = 0;
  }
  if (tid == 255) bsum[blockIdx.x] = add + x; // block total
  // fused log-degree sum
  float lv = (i < N) ? logf((float)(v + 1)) : 0.f;
  for (int o = 32; o > 0; o >>= 1) lv += __shfl_down(lv, o, 64);
  if (lane == 0) fsum[wv] = lv;
  __syncthreads();
  if (tid == 0) atomicAdd(meanacc, fsum[0] + fsum[1] + fsum[2] + fsum[3]);
}

// B) scan the block sums (1 wave handles up to 128 blocks)
__global__ void k_scanB(const int* __restrict__ bsum, int* boff, int* row_start) {
  int lane = threadIdx.x;           // 64
  int a0 = (lane < NSCB) ? bsum[lane] : 0;
  int a1 = (64 + lane < NSCB) ? bsum[64 + lane] : 0;
  int x = a0;
  for (int o = 1; o < 64; o <<= 1) {
    int y = __shfl_up(x, o, 64);
    if (lane >= o) x += y;
  }
  int tot0 = __shfl(x, 63, 64);
  int x1 = a1;
  for (int o = 1; o < 64; o <<= 1) {
    int y = __shfl_up(x1, o, 64);
    if (lane >= o) x1 += y;
  }
  if (lane < NSCB) boff[lane] = x - a0;
  if (64 + lane < NSCB) boff[64 + lane] = tot0 + x1 - a1;
  if (lane == 63) row_start[N] = tot0 + __shfl(x1, 63, 64);   // == E
}

// C) add block offsets
__global__ void k_scanC(int* row_start, const int* __restrict__ boff) {
  int i = blockIdx.x * 256 + threadIdx.x;
  if (i < N) row_start[i] += boff[blockIdx.x];
}

// scatter edges into CSR slots; pack src | (type<<16)
__global__ void k_scatter(const int* __restrict__ edge_src, const int* __restrict__ edge_dst,
                          const int* __restrict__ edge_type, const int* __restrict__ row_start,
                          int* fill, int* packed) {
  int e = blockIdx.x * blockDim.x + threadIdx.x;
  if (e < E) {
    int dn = edge_dst[e];
    int pos = atomicAdd(&fill[dn], 1);
    packed[row_start[dn] + pos] = edge_src[e] | (edge_type[e] << 16);
  }
}

__global__ void k_scales(const int* __restrict__ cnt, const float* __restrict__ meanacc,
                         float* scales) {
  int i = blockIdx.x * blockDim.x + threadIdx.x;
  if (i < N) {
    float m = meanacc[0] / (float)N;
    float s = logf((float)(cnt[i] + 1)) / m;
    scales[i * 3 + 0] = 1.f;
    scales[i * 3 + 1] = s;
    scales[i * 3 + 2] = 1.f / fmaxf(s, 0.01f);
  }
}

// fused prep: rel (fp16) + split weights (bf16 hi/lo)
__global__ void k_prep(const float* __restrict__ query, const float* __restrict__ Wr,
                       const float* __restrict__ br, _Float16* rel,
                       const float* __restrict__ Wl, short* WT) {
  int o = blockIdx.x * blockDim.x + threadIdx.x;
  if (o < RELSZ) {
    int d = o & 31;
    int r = (o >> 5) % R2;
    int b = (o / (R2 * D)) % B;
    int l = o / (B * R2 * D);
    int rd = r * D + d;
    const float4* wrow = (const float4*)(Wr + ((size_t)l * R2 * D + rd) * D);
    const float* q = query + b * D;
    float acc = br[l * R2 * D + rd];
#pragma unroll
    for (int k = 0; k < 8; ++k) {
      float4 w4 = wrow[k];
      acc = fmaf(q[4 * k + 0], w4.x, acc);
      acc = fmaf(q[4 * k + 1], w4.y, acc);
      acc = fmaf(q[4 * k + 2], w4.z, acc);
      acc = fmaf(q[4 * k + 3], w4.w, acc);
    }
    rel[o] = (_Float16)acc;
    return;
  }
  int t0 = o - RELSZ;
  if (t0 >= L * 13312) return;
  int l = t0 / 13312, t = t0 % 13312;
  int j = t / 416, k = t % 416;
  float v = Wl[(size_t)l * 13312 + j * 416 + k];
  unsigned short hi, lo;
  split2(v, hi, lo);
  short* wt = WT + (size_t)l * WSZ;
  if (k < 32) {
    int dx = j * 32 + k;
    wt[dx] = (short)hi;
    wt[1024 + dx] = (short)lo;
  } else {
    int u = k - 32;
    int f = u / 3, s = u % 3;
    int df = (s * 32 + j) * 128 + f;
    wt[2048 + df] = (short)hi;
    wt[14336 + df] = (short)lo;
  }
}

// ---- aggregation kernel: 128 threads = 2 waves = 2 nodes per block ----
// Small blocks minimize max-of-degree retirement penalty. Lane covers 4
// channels (fp16x4). Unpredicated full batches of 8 edges; tail batch uses
// the SAME packed path with wave-uniform branches (cntE uniform per wave ->
// s_cbranch, zero cndmask). Stats -> single bf16 panel.
__global__ __launch_bounds__(128) void k_agg(
    const _Float16* __restrict__ xin, const _Float16* __restrict__ rel_l,
    short* __restrict__ stath,
    const int* __restrict__ row_start, const int* __restrict__ packed,
    const int* __restrict__ h_index, const float* __restrict__ query) {
  int tid = threadIdx.x;
  int lane = tid & 63;
  int wv = __builtin_amdgcn_readfirstlane(tid >> 6);   // 0..1
  int node = blockIdx.x * 2 + wv;

  int ch4 = 4 * lane;
  int b = lane >> 3;
  int d0 = ch4 & 31;
  int hb = h_index[b];
  const _Float16* relb4 = rel_l + b * (R2 * D) + d0;
  const _Float16* xch = xin + ch4;
  int rs = row_start[node];
  int cntE = row_start[node + 1] - rs;

  float4_t s1 = {0.f, 0.f, 0.f, 0.f}, s2 = {0.f, 0.f, 0.f, 0.f};
  half4_t mxh = {(_Float16)-INFINITY, (_Float16)-INFINITY, (_Float16)-INFINITY, (_Float16)-INFINITY};
  half4_t mnh = {(_Float16)INFINITY, (_Float16)INFINITY, (_Float16)INFINITY, (_Float16)INFINITY};

  auto accp = [&](half4_t xv, half4_t rv) {      // packed-fp16 accumulate
    half4_t m = xv * rv;                         // v_pk_mul_f16 x2
    mxh = __builtin_elementwise_max(mxh, m);     // v_pk_max_f16 x2
    mnh = __builtin_elementwise_min(mnh, m);     // v_pk_min_f16 x2
    float4_t mf = __builtin_convertvector(m, float4_t);
#pragma unroll
    for (int c = 0; c < 4; ++c) {
      s1[c] += mf[c];
      s2[c] = fmaf(mf[c], mf[c], s2[c]);
    }
  };

  // -------- main loop: full batches, no predication --------
  int nfull = cntE >> 3;
  for (int t = 0; t < nfull; ++t) {
    int j0 = t * 8;
    int pk[8];
#pragma unroll
    for (int u = 0; u < 8; ++u) pk[u] = packed[rs + j0 + u];   // uniform -> s_load
    half4_t xv[8], rv[8];
#pragma unroll
    for (int u = 0; u < 8; ++u) xv[u] = *(const half4_t*)&xch[(pk[u] & 0xFFFF) * BD];
#pragma unroll
    for (int u = 0; u < 8; ++u) rv[u] = *(const half4_t*)&relb4[(pk[u] >> 16) * D];
#pragma unroll
    for (int u = 0; u < 8; ++u) accp(xv[u], rv[u]);
  }
  // -------- tail: clamped batch, wave-uniform guards (no masks) --------
  int rem = cntE & 7;
  if (rem) {
    int j0 = nfull * 8;
    int last = cntE - 1;
    int pk[8];
#pragma unroll
    for (int u = 0; u < 8; ++u) {
      int jj = j0 + u;
      pk[u] = packed[rs + (jj < cntE ? jj : last)];
    }
    half4_t xv[8], rv[8];
#pragma unroll
    for (int u = 0; u < 8; ++u) xv[u] = *(const half4_t*)&xch[(pk[u] & 0xFFFF) * BD];
#pragma unroll
    for (int u = 0; u < 8; ++u) rv[u] = *(const half4_t*)&relb4[(pk[u] >> 16) * D];
    // rem is wave-uniform -> each guard is an s_cbranch, no lane masking
#pragma unroll
    for (int u = 0; u < 7; ++u)
      if (u < rem) accp(xv[u], rv[u]);
  }
  // -------- boundary self-message + finalize (f32) --------
  float4_t mxF = __builtin_convertvector(mxh, float4_t);
  float4_t mnF = __builtin_convertvector(mnh, float4_t);
  {
    const float* q4 = &query[ch4];
    bool isb = (hb == node);
#pragma unroll
    for (int c = 0; c < 4; ++c) {
      float m = isb ? q4[c] : 0.f;
      s1[c] += m;
      s2[c] = fmaf(m, m, s2[c]);
      mxF[c] = fmaxf(mxF[c], m);
      mnF[c] = fminf(mnF[c], m);
    }
  }
  float invdeg = 1.f / (float)(cntE + 1);

  unsigned int hw[8];
#pragma unroll
  for (int c = 0; c < 4; ++c) {
    float mean = s1[c] * invdeg, sq = s2[c] * invdeg;
    float sd = sqrtf(fmaxf(sq - mean * mean, EPSF));
    unsigned short h0 = f2bf(mean), h1 = f2bf(mxF[c]);
    unsigned short h2 = f2bf(mnF[c]), h3 = f2bf(sd);
    hw[2 * c]     = (unsigned)h0 | ((unsigned)h1 << 16);
    hw[2 * c + 1] = (unsigned)h2 | ((unsigned)h3 << 16);
  }
  int grp = node >> 3;
  int r = (node & 7) * 8 + b;               // panel row (node_local*8 + b)
  short* dh = stath + (size_t)grp * SBLK + r * 128 + 4 * d0;
  *(uint4*)dh = make_uint4(hw[0], hw[1], hw[2], hw[3]);
  *(uint4*)(dh + 8) = make_uint4(hw[4], hw[5], hw[6], hw[7]);
}

// ---- GEMM kernel: B register-resident (feat weights single bf16),
// GPB=10 (250 blocks), A double-buffer prefetch, no VGPR cap (proven
// (512,2) config -> no spills; ~130 VGPR natural).
struct AFrag {
  bf16x8 AH[4];
  half8_t xv;
};

__global__ __launch_bounds__(512, 2) void k_gemm(
    const _Float16* __restrict__ xin, _Float16* __restrict__ xout,
    const short* __restrict__ stath,
    const short* __restrict__ WT_l, const float* __restrict__ bl_l,
    const float* __restrict__ scales) {
  int tid = threadIdx.x;
  int lane = tid & 63;
  int wv = __builtin_amdgcn_readfirstlane(tid >> 6);   // 0..7
  int mt = wv >> 1, nt = wv & 1;
  int li = lane & 15, kg = lane >> 4;
  int rowA = mt * 16 + li;
  int jc = nt * 16 + li;

  const short* wxh = WT_l;
  const short* wxl = WT_l + 1024;
  const short* wfh = WT_l + 2048;

  // B fragments: loaded ONCE (x hi/lo + feat hi only = 14 frags = 56 VGPR)
  bf16x8 BXH = *(const bf16x8*)&wxh[jc * 32 + kg * 8];
  bf16x8 BXL = *(const bf16x8*)&wxl[jc * 32 + kg * 8];
  bf16x8 BH[4][3];
#pragma unroll
  for (int step = 0; step < 4; ++step)
#pragma unroll
    for (int s = 0; s < 3; ++s)
      BH[step][s] = *(const bf16x8*)&wfh[s * 4096 + jc * 128 + step * 32 + kg * 8];

  int grp0 = blockIdx.x * GPB;

  auto loadA = [&](int g) {
    AFrag a;
    int grp = grp0 + g;
    const short* sh = stath + (size_t)grp * SBLK + rowA * 128 + kg * 8;
#pragma unroll
    for (int step = 0; step < 4; ++step) a.AH[step] = *(const bf16x8*)&sh[step * 32];
    a.xv = *(const half8_t*)&xin[(grp * NPB) * 256 + rowA * 32 + kg * 8];
    return a;
  };

  AFrag cur = loadA(0);
#pragma unroll
  for (int g = 0; g < GPB; ++g) {
    AFrag nxt;
    if (g + 1 < GPB) nxt = loadA(g + 1);   // issue next-group loads early

    int node0 = (grp0 + g) * NPB;
    bf16x8 axh, axl;
#pragma unroll
    for (int i = 0; i < 8; ++i) {
      unsigned short h, lo;
      split2((float)cur.xv[i], h, lo);     // fp16 -> bf16 hi/lo exact
      axh[i] = (short)h;
      axl[i] = (short)lo;
    }

    f32x4 acc0 = {0.f, 0.f, 0.f, 0.f};
    f32x4 acc1 = {0.f, 0.f, 0.f, 0.f};
    f32x4 acc2 = {0.f, 0.f, 0.f, 0.f};

    acc0 = __builtin_amdgcn_mfma_f32_16x16x32_bf16(axl, BXH, acc0, 0, 0, 0);
    acc0 = __builtin_amdgcn_mfma_f32_16x16x32_bf16(axh, BXL, acc0, 0, 0, 0);
    acc0 = __builtin_amdgcn_mfma_f32_16x16x32_bf16(axh, BXH, acc0, 0, 0, 0);
#pragma unroll
    for (int step = 0; step < 4; ++step) {
      acc0 = __builtin_amdgcn_mfma_f32_16x16x32_bf16(cur.AH[step], BH[step][0], acc0, 0, 0, 0);
      acc1 = __builtin_amdgcn_mfma_f32_16x16x32_bf16(cur.AH[step], BH[step][1], acc1, 0, 0, 0);
      acc2 = __builtin_amdgcn_mfma_f32_16x16x32_bf16(cur.AH[step], BH[step][2], acc2, 0, 0, 0);
    }

    // epilogue: scales per row, bias, relu, fp16 store
    // C/D layout: col = lane&15, row = (lane>>4)*4 + reg
    int rbase = mt * 16 + kg * 4;
    int node = node0 + (rbase >> 3);
    float sc1 = scales[node * 3 + 1];
    float sc2 = scales[node * 3 + 2];
    float bias = bl_l[jc & 31];
#pragma unroll
    for (int reg = 0; reg < 4; ++reg) {
      float v = acc0[reg] + sc1 * acc1[reg] + sc2 * acc2[reg] + bias;
      xout[node0 * 256 + (rbase + reg) * 32 + jc] = (_Float16)fmaxf(v, 0.f);
    }
    cur = nxt;
  }
}

// -------------- scoring head: one block per (b, neg) --------------
__global__ void k_score(const _Float16* __restrict__ xL, const float* __restrict__ query,
                        const int* __restrict__ t_index, const float* __restrict__ W1,
                        const float* __restrict__ b1, const float* __restrict__ W2,
                        const float* __restrict__ b2, float* outp) {
  int bn = blockIdx.x;             // b*NEG + neg
  int b = bn >> 5;
  int j = threadIdx.x;             // 64
  __shared__ float f[64];
  int t = t_index[bn];
  f[j] = (j < 32) ? (float)xL[t * BD + b * D + j] : query[b * D + (j - 32)];
  __syncthreads();
  const float* w1r = W1 + j * 64;
  float h = b1[j];
#pragma unroll
  for (int k = 0; k < 64; ++k) h = fmaf(f[k], w1r[k], h);
  h = fmaxf(h, 0.f);
  float p = h * W2[j];
#pragma unroll
  for (int o = 32; o > 0; o >>= 1) p += __shfl_down(p, o, 64);
  if (j == 0) outp[bn] = p + b2[0];
}

} // namespace

extern "C" void kernel_launch(void* const* d_in, const int* in_sizes, int n_in,
                              void* d_out, int out_size, void* d_ws, size_t ws_size,
                              hipStream_t stream) {
  const int* edge_src   = (const int*)d_in[0];
  const int* edge_dst   = (const int*)d_in[1];
  const int* edge_type  = (const int*)d_in[2];
  const int* h_index    = (const int*)d_in[3];
  const int* t_index    = (const int*)d_in[4];
  const int* r_index    = (const int*)d_in[5];
  const float* query_emb= (const float*)d_in[6];
  const float* Wr       = (const float*)d_in[7];
  const float* br       = (const float*)d_in[8];
  const float* Wl       = (const float*)d_in[9];
  const float* bl       = (const float*)d_in[10];
  const float* W1       = (const float*)d_in[11];
  const float* b1       = (const float*)d_in[12];
  const float* W2       = (const float*)d_in[13];
  const float* b2       = (const float*)d_in[14];
  float* outp = (float*)d_out;
  (void)in_sizes; (void)n_in; (void)out_size; (void)ws_size;

  char* w = (char*)d_ws;
  auto alloc = [&](size_t bytes) {
    char* p = w;
    w += (bytes + 511) & ~(size_t)511;
    return p;
  };
  _Float16* x0   = (_Float16*)alloc(sizeof(_Float16) * N * BD);
  _Float16* x1   = (_Float16*)alloc(sizeof(_Float16) * N * BD);
  short* stath   = (short*)alloc(sizeof(short) * (size_t)NBLK * SBLK);
  _Float16* rel  = (_Float16*)alloc(sizeof(_Float16) * RELSZ);
  short* WT      = (short*)alloc(sizeof(short) * L * WSZ);
  float* query   = (float*)alloc(sizeof(float) * BD);
  float* scales  = (float*)alloc(sizeof(float) * N * 3);
  float* meanacc = (float*)alloc(sizeof(float) * 16);
  int* row_start = (int*)alloc(sizeof(int) * (N + 1));
  int* cnt       = (int*)alloc(sizeof(int) * N);
  int* fill      = (int*)alloc(sizeof(int) * N);
  int* packed    = (int*)alloc(sizeof(int) * E);
  int* bsum      = (int*)alloc(sizeof(int) * 128);
  int* boff      = (int*)alloc(sizeof(int) * 128);

  k_init<<<2048, 256, 0, stream>>>((unsigned int*)x0, cnt, meanacc);
  k_countq<<<(E + 255) / 256 + 1, 256, 0, stream>>>(edge_dst, cnt, r_index, h_index,
                                                    query_emb, query, x0);
  k_scanA<<<NSCB, 256, 0, stream>>>(cnt, row_start, bsum, fill, meanacc);
  k_scanB<<<1, 64, 0, stream>>>(bsum, boff, row_start);
  k_scanC<<<NSCB, 256, 0, stream>>>(row_start, boff);
  k_scatter<<<(E + 255) / 256, 256, 0, stream>>>(edge_src, edge_dst, edge_type,
                                                 row_start, fill, packed);
  k_scales<<<(N + 255) / 256, 256, 0, stream>>>(cnt, meanacc, scales);
  k_prep<<<(RELSZ + L * 13312 + 255) / 256, 256, 0, stream>>>(query, Wr, br, rel, Wl, WT);

  const _Float16* xin = x0;
  _Float16* xout = x1;
  for (int l = 0; l < L; ++l) {
    k_agg<<<N / 2, 128, 0, stream>>>(xin, rel + (size_t)l * B * R2 * D,
                                     stath, row_start, packed, h_index, query);
    k_gemm<<<GBLK, 512, 0, stream>>>(xin, xout, stath,
                                     WT + (size_t)l * WSZ, bl + l * D, scales);
    const _Float16* t = xout;
    xout = (_Float16*)xin;
    xin = t;
  }
  // L is even -> final activations are back in x0 (== xin after last swap)
  k_score<<<B * NEG, 64, 0, stream>>>(xin, query, t_index, W1, b1, W2, b2, outp);
}